// Round 1
// baseline (202.140 us; speedup 1.0000x reference)
//
#include <hip/hip_runtime.h>
#include <hip/hip_bf16.h>
#include <cstddef>

// ---------- types / helpers ----------
typedef __attribute__((ext_vector_type(8))) short bf16x8;
typedef __attribute__((ext_vector_type(4))) float f32x4;

static __device__ __forceinline__ unsigned short f2bf(float f) {
    unsigned int u = __float_as_uint(f);
    u += 0x7fffu + ((u >> 16) & 1u);
    return (unsigned short)(u >> 16);
}
static __device__ __forceinline__ float bf2f(unsigned short h) {
    return __uint_as_float(((unsigned int)h) << 16);
}

#define B_ 8
#define S_ 1000
#define H_ 768
#define NH_ 12
#define HD_ 64
#define M_ 8000
#define HC_ 2304   // 3*768

// ---------- kernel 1: x = features + pos_emb * scale, cast to bf16 ----------
__global__ __launch_bounds__(256)
void prep_x_kernel(const float* __restrict__ feat, const float* __restrict__ pos,
                   const int* __restrict__ level, unsigned short* __restrict__ xb) {
    size_t e = ((size_t)blockIdx.x * blockDim.x + threadIdx.x) * 4;
    if (e >= (size_t)M_ * H_) return;
    float sc = 1.0f + 0.1f * (float)level[0];
    const float4 f = *reinterpret_cast<const float4*>(&feat[e]);
    size_t pe = e % ((size_t)S_ * H_);
    const float4 p = *reinterpret_cast<const float4*>(&pos[pe]);
    ushort4 o;
    o.x = f2bf(f.x + sc * p.x);
    o.y = f2bf(f.y + sc * p.y);
    o.z = f2bf(f.z + sc * p.z);
    o.w = f2bf(f.w + sc * p.w);
    *reinterpret_cast<ushort4*>(&xb[e]) = o;
}

// ---------- kernel 2: cast Wq|Wk|Wv|Wo (each [768][768] row-major) to bf16, concat ----------
__global__ __launch_bounds__(256)
void wconv_kernel(const float* __restrict__ wq, const float* __restrict__ wk,
                  const float* __restrict__ wv, const float* __restrict__ wo,
                  unsigned short* __restrict__ dst) {
    size_t e = ((size_t)blockIdx.x * blockDim.x + threadIdx.x) * 4;
    const size_t WSZ = (size_t)H_ * H_;
    if (e >= 4 * WSZ) return;
    const float* src; size_t off;
    if (e < WSZ)          { src = wq; off = e; }
    else if (e < 2 * WSZ) { src = wk; off = e - WSZ; }
    else if (e < 3 * WSZ) { src = wv; off = e - 2 * WSZ; }
    else                  { src = wo; off = e - 3 * WSZ; }
    const float4 f = *reinterpret_cast<const float4*>(&src[off]);
    ushort4 o;
    o.x = f2bf(f.x); o.y = f2bf(f.y); o.z = f2bf(f.z); o.w = f2bf(f.w);
    *reinterpret_cast<ushort4*>(&dst[e]) = o;
}

// ---------- kernel 3/5: bf16 MFMA GEMM, C = A[M,K] * B[N,K]^T + epilogue ----------
// EPI 0: bias select over {b0,b1,b2} per 768-col group, write bf16 to outB
// EPI 1: bias b0 + residual, write fp32 to outF
#define BM 128
#define BN 128
#define BK 32

template<int EPI>
__global__ __launch_bounds__(256)
void gemm_bt_kernel(const unsigned short* __restrict__ A,  // [M][K] bf16
                    const unsigned short* __restrict__ B,  // [N][K] bf16
                    int M, int N, int K,
                    const float* __restrict__ b0, const float* __restrict__ b1,
                    const float* __restrict__ b2,
                    const float* __restrict__ resid,
                    unsigned short* __restrict__ outB, float* __restrict__ outF) {
    __shared__ unsigned short As[BM][BK + 8];
    __shared__ unsigned short Bs[BN][BK + 8];
    const int tid  = threadIdx.x;
    const int lane = tid & 63;
    const int wid  = tid >> 6;
    const int wm = wid >> 1, wn = wid & 1;          // 2x2 wave grid, 64x64 per wave
    const int bm = blockIdx.y * BM;
    const int bn = blockIdx.x * BN;
    const int fr = lane & 15, fq = lane >> 4;

    f32x4 acc[4][4] = {};

    for (int k0 = 0; k0 < K; k0 += BK) {
#pragma unroll
        for (int t = 0; t < 2; ++t) {
            int ci = tid + t * 256;                  // 512 chunks of 8 bf16
            int r = ci >> 2, cc = (ci & 3) * 8;
            int gr = bm + r;
            bf16x8 va = {};
            if (gr < M) va = *reinterpret_cast<const bf16x8*>(&A[(size_t)gr * K + k0 + cc]);
            *reinterpret_cast<bf16x8*>(&As[r][cc]) = va;
            int gn = bn + r;
            bf16x8 vb = {};
            if (gn < N) vb = *reinterpret_cast<const bf16x8*>(&B[(size_t)gn * K + k0 + cc]);
            *reinterpret_cast<bf16x8*>(&Bs[r][cc]) = vb;
        }
        __syncthreads();

        bf16x8 af[4], bfr[4];
#pragma unroll
        for (int m = 0; m < 4; ++m)
            af[m] = *reinterpret_cast<const bf16x8*>(&As[wm * 64 + m * 16 + fr][fq * 8]);
#pragma unroll
        for (int n = 0; n < 4; ++n)
            bfr[n] = *reinterpret_cast<const bf16x8*>(&Bs[wn * 64 + n * 16 + fr][fq * 8]);
#pragma unroll
        for (int m = 0; m < 4; ++m)
#pragma unroll
            for (int n = 0; n < 4; ++n)
                acc[m][n] = __builtin_amdgcn_mfma_f32_16x16x32_bf16(af[m], bfr[n], acc[m][n], 0, 0, 0);
        __syncthreads();
    }

    // epilogue + store: C[row][col], row = bm+wm*64+m*16+fq*4+j, col = bn+wn*64+n*16+fr
#pragma unroll
    for (int m = 0; m < 4; ++m) {
#pragma unroll
        for (int n = 0; n < 4; ++n) {
            int col = bn + wn * 64 + n * 16 + fr;
#pragma unroll
            for (int j = 0; j < 4; ++j) {
                int row = bm + wm * 64 + m * 16 + fq * 4 + j;
                if (row >= M) continue;
                float v = acc[m][n][j];
                if (EPI == 0) {
                    float bias = (col < 768) ? b0[col] : (col < 1536) ? b1[col - 768] : b2[col - 1536];
                    outB[(size_t)row * N + col] = f2bf(v + bias);
                } else {
                    v += b0[col] + resid[(size_t)row * N + col];
                    outF[(size_t)row * N + col] = v;
                }
            }
        }
    }
}

// ---------- kernel 4: banded attention, one wave per query ----------
__global__ __launch_bounds__(256)
void attn_kernel(const unsigned short* __restrict__ QKV,  // [M][2304] bf16: Q|K|V
                 unsigned short* __restrict__ ctx,        // [M][768] bf16
                 const int* __restrict__ level_p) {
    const int lane = threadIdx.x & 63;
    const int wv = threadIdx.x >> 6;
    int chunk = blockIdx.x;                 // B * NH * (S/4)
    int qi4 = chunk % 250;
    int h = (chunk / 250) % NH_;
    int b = chunk / (250 * NH_);
    int i = qi4 * 4 + wv;
    int lev = level_p[0];
    int w = (lev == 0) ? 2 : (lev == 1) ? 5 : S_;

    size_t mrow = (size_t)(b * S_ + i);
    float q = bf2f(QKV[mrow * HC_ + h * HD_ + lane]);
    int j0 = max(0, i - w), j1 = min(S_ - 1, i + w);

    float mx = -1e30f, l = 0.f, acc = 0.f;
    for (int j = j0; j <= j1; ++j) {
        size_t kr = (size_t)(b * S_ + j) * HC_ + 768 + h * HD_ + lane;
        float kv = bf2f(QKV[kr]);
        float p = q * kv;
#pragma unroll
        for (int o = 32; o; o >>= 1) p += __shfl_xor(p, o);
        p *= 0.125f;                         // 1/sqrt(64)
        float vv = bf2f(QKV[kr + 768]);
        float mn = fmaxf(mx, p);
        float corr = __expf(mx - mn);
        float e = __expf(p - mn);
        l = l * corr + e;
        acc = acc * corr + e * vv;
        mx = mn;
    }
    ctx[mrow * (size_t)H_ + h * HD_ + lane] = f2bf(acc / l);
}

// ---------- kernel 6: in-place LayerNorm over rows of d_out ----------
__global__ __launch_bounds__(256)
void ln_kernel(float* __restrict__ y, const float* __restrict__ g, const float* __restrict__ bta) {
    int row = blockIdx.x;
    int tid = threadIdx.x;
    float* p = y + (size_t)row * H_;
    float v[3];
    float s = 0.f, s2 = 0.f;
#pragma unroll
    for (int t = 0; t < 3; ++t) {
        v[t] = p[tid + t * 256];
        s += v[t];
        s2 += v[t] * v[t];
    }
#pragma unroll
    for (int o = 32; o; o >>= 1) {
        s  += __shfl_xor(s, o);
        s2 += __shfl_xor(s2, o);
    }
    __shared__ float ss[4], ss2[4];
    if ((tid & 63) == 0) { ss[tid >> 6] = s; ss2[tid >> 6] = s2; }
    __syncthreads();
    s  = ss[0] + ss[1] + ss[2] + ss[3];
    s2 = ss2[0] + ss2[1] + ss2[2] + ss2[3];
    float mu = s * (1.f / H_);
    float var = s2 * (1.f / H_) - mu * mu;
    float rs = rsqrtf(var + 1e-5f);
#pragma unroll
    for (int t = 0; t < 3; ++t) {
        int c = tid + t * 256;
        p[c] = (v[t] - mu) * rs * g[c] + bta[c];
    }
}

// ---------- launch ----------
extern "C" void kernel_launch(void* const* d_in, const int* in_sizes, int n_in,
                              void* d_out, int out_size, void* d_ws, size_t ws_size,
                              hipStream_t stream) {
    const float* feat  = (const float*)d_in[0];
    const float* pos   = (const float*)d_in[1];
    const float* Wq    = (const float*)d_in[2];
    const float* bq    = (const float*)d_in[3];
    const float* Wk    = (const float*)d_in[4];
    const float* bk    = (const float*)d_in[5];
    const float* Wv    = (const float*)d_in[6];
    const float* bv    = (const float*)d_in[7];
    const float* Wo    = (const float*)d_in[8];
    const float* bo    = (const float*)d_in[9];
    const float* ln_g  = (const float*)d_in[10];
    const float* ln_b  = (const float*)d_in[11];
    const int*   level = (const int*)d_in[12];
    float* out = (float*)d_out;

    // workspace layout (bf16 buffers as ushort)
    char* ws = (char*)d_ws;
    unsigned short* xb   = (unsigned short*)ws;                      // [8000][768]
    unsigned short* Wcat = xb + (size_t)M_ * H_;                     // [3072][768] = Wq|Wk|Wv|Wo
    unsigned short* QKVb = Wcat + (size_t)4 * H_ * H_;               // [8000][2304]
    unsigned short* ctxb = QKVb + (size_t)M_ * HC_;                  // [8000][768]

    // 1) x = features + pos_emb * scale  (bf16)
    prep_x_kernel<<<(M_ * H_ / 4 + 255) / 256, 256, 0, stream>>>(feat, pos, level, xb);
    // 2) weights -> bf16
    wconv_kernel<<<(4 * H_ * H_ / 4 + 255) / 256, 256, 0, stream>>>(Wq, Wk, Wv, Wo, Wcat);
    // 3) QKV = x @ [Wq|Wk|Wv]^T + bias   (bf16 out)
    gemm_bt_kernel<0><<<dim3(HC_ / BN, (M_ + BM - 1) / BM), 256, 0, stream>>>(
        xb, Wcat, M_, HC_, H_, bq, bk, bv, nullptr, QKVb, nullptr);
    // 4) banded attention -> ctx (bf16)
    attn_kernel<<<B_ * NH_ * (S_ / 4), 256, 0, stream>>>(QKVb, ctxb, level);
    // 5) y = ctx @ Wo^T + bo + features  (fp32 into d_out)
    gemm_bt_kernel<1><<<dim3(H_ / BN, (M_ + BM - 1) / BM), 256, 0, stream>>>(
        ctxb, Wcat + (size_t)3 * H_ * H_, M_, H_, H_, bo, nullptr, nullptr, feat, nullptr, out);
    // 6) LayerNorm in place on d_out
    ln_kernel<<<M_, 256, 0, stream>>>(out, ln_g, ln_b);
}

// Round 2
// 175.804 us; speedup vs baseline: 1.1498x; 1.1498x over previous
//
#include <hip/hip_runtime.h>
#include <hip/hip_bf16.h>
#include <cstddef>

// ---------- types / helpers ----------
typedef __attribute__((ext_vector_type(8))) short bf16x8;
typedef __attribute__((ext_vector_type(4))) float f32x4;

static __device__ __forceinline__ unsigned short f2bf(float f) {
    unsigned int u = __float_as_uint(f);
    u += 0x7fffu + ((u >> 16) & 1u);
    return (unsigned short)(u >> 16);
}
static __device__ __forceinline__ float bf2f(unsigned short h) {
    return __uint_as_float(((unsigned int)h) << 16);
}

#define B_ 8
#define S_ 1000
#define H_ 768
#define NH_ 12
#define HD_ 64
#define M_ 8000
#define HC_ 2304   // 3*768

// ---------- kernel 1: x = features + pos_emb * scale, cast to bf16 ----------
__global__ __launch_bounds__(256)
void prep_x_kernel(const float* __restrict__ feat, const float* __restrict__ pos,
                   const int* __restrict__ level, unsigned short* __restrict__ xb) {
    size_t e = ((size_t)blockIdx.x * blockDim.x + threadIdx.x) * 4;
    if (e >= (size_t)M_ * H_) return;
    float sc = 1.0f + 0.1f * (float)level[0];
    const float4 f = *reinterpret_cast<const float4*>(&feat[e]);
    size_t pe = e % ((size_t)S_ * H_);
    const float4 p = *reinterpret_cast<const float4*>(&pos[pe]);
    ushort4 o;
    o.x = f2bf(f.x + sc * p.x);
    o.y = f2bf(f.y + sc * p.y);
    o.z = f2bf(f.z + sc * p.z);
    o.w = f2bf(f.w + sc * p.w);
    *reinterpret_cast<ushort4*>(&xb[e]) = o;
}

// ---------- kernel 2: cast Wq|Wk|Wv|Wo (each [768][768] row-major) to bf16, concat ----------
__global__ __launch_bounds__(256)
void wconv_kernel(const float* __restrict__ wq, const float* __restrict__ wk,
                  const float* __restrict__ wv, const float* __restrict__ wo,
                  unsigned short* __restrict__ dst) {
    size_t e = ((size_t)blockIdx.x * blockDim.x + threadIdx.x) * 4;
    const size_t WSZ = (size_t)H_ * H_;
    if (e >= 4 * WSZ) return;
    const float* src; size_t off;
    if (e < WSZ)          { src = wq; off = e; }
    else if (e < 2 * WSZ) { src = wk; off = e - WSZ; }
    else if (e < 3 * WSZ) { src = wv; off = e - 2 * WSZ; }
    else                  { src = wo; off = e - 3 * WSZ; }
    const float4 f = *reinterpret_cast<const float4*>(&src[off]);
    ushort4 o;
    o.x = f2bf(f.x); o.y = f2bf(f.y); o.z = f2bf(f.z); o.w = f2bf(f.w);
    *reinterpret_cast<ushort4*>(&dst[e]) = o;
}

// ---------- kernel 3/5: bf16 MFMA GEMM (m97 structure), C = A[M,K]*B[N,K]^T + epilogue ----------
// EPI 0: bias select over {b0,b1,b2} per 768-col group, write bf16 to outB
// EPI 1: bias b0 + residual, write fp32 to outF
#define BM 128
#define BN 128
#define BK 32

template<int EPI>
__global__ __launch_bounds__(256)
void gemm_bt_kernel(const unsigned short* __restrict__ A,  // [M][K] bf16
                    const unsigned short* __restrict__ B,  // [N][K] bf16
                    int M, int N, int K,
                    const float* __restrict__ b0, const float* __restrict__ b1,
                    const float* __restrict__ b2,
                    const float* __restrict__ resid,
                    unsigned short* __restrict__ outB, float* __restrict__ outF) {
    // linear LDS (no pad): 64 B rows -> fragment ds_read_b128 covers a
    // contiguous 1 KiB block per wave (fr*64 + fq*16 bijective) = conflict-free
    __shared__ unsigned short As[BM][BK];
    __shared__ unsigned short Bs[BN][BK];
    const int tid  = threadIdx.x;
    const int lane = tid & 63;
    const int wid  = tid >> 6;
    const int wm = wid >> 1, wn = wid & 1;          // 2x2 wave grid, 64x64 per wave
    const int bm = blockIdx.y * BM;
    const int bn = blockIdx.x * BN;
    const int fr = lane & 15, fq = lane >> 4;

    // staging: per global_load_lds, wave writes LDS base + lane*16B
    // -> row = lane>>2 (64 B rows), col = (lane&3)*8 elems
    const int srow = lane >> 2;
    const int scol = (lane & 3) * 8;

    f32x4 acc[4][4] = {};

    for (int k0 = 0; k0 < K; k0 += BK) {
#pragma unroll
        for (int t = 0; t < 2; ++t) {
            const int l = wid + t * 4;               // 8 chunks of 16 rows
            int ar = bm + l * 16 + srow;
            ar = ar < M ? ar : M - 1;                // clamp: garbage rows land in out-rows >= M (skipped)
            const unsigned short* ga = A + (size_t)ar * K + k0 + scol;
            __builtin_amdgcn_global_load_lds(
                (const __attribute__((address_space(1))) unsigned int*)ga,
                (__attribute__((address_space(3))) unsigned int*)&As[l * 16][0], 16, 0, 0);
            const int br = bn + l * 16 + srow;       // N is a multiple of 128
            const unsigned short* gb = B + (size_t)br * K + k0 + scol;
            __builtin_amdgcn_global_load_lds(
                (const __attribute__((address_space(1))) unsigned int*)gb,
                (__attribute__((address_space(3))) unsigned int*)&Bs[l * 16][0], 16, 0, 0);
        }
        __syncthreads();

        bf16x8 af[4], bfr[4];
#pragma unroll
        for (int m = 0; m < 4; ++m)
            af[m] = *reinterpret_cast<const bf16x8*>(&As[wm * 64 + m * 16 + fr][fq * 8]);
#pragma unroll
        for (int n = 0; n < 4; ++n)
            bfr[n] = *reinterpret_cast<const bf16x8*>(&Bs[wn * 64 + n * 16 + fr][fq * 8]);
#pragma unroll
        for (int m = 0; m < 4; ++m)
#pragma unroll
            for (int n = 0; n < 4; ++n)
                acc[m][n] = __builtin_amdgcn_mfma_f32_16x16x32_bf16(af[m], bfr[n], acc[m][n], 0, 0, 0);
        __syncthreads();
    }

    // epilogue + store: C[row][col], row = bm+wm*64+m*16+fq*4+j, col = bn+wn*64+n*16+fr
#pragma unroll
    for (int m = 0; m < 4; ++m) {
#pragma unroll
        for (int n = 0; n < 4; ++n) {
            int col = bn + wn * 64 + n * 16 + fr;
#pragma unroll
            for (int j = 0; j < 4; ++j) {
                int row = bm + wm * 64 + m * 16 + fq * 4 + j;
                if (row >= M) continue;
                float v = acc[m][n][j];
                if (EPI == 0) {
                    float bias = (col < 768) ? b0[col] : (col < 1536) ? b1[col - 768] : b2[col - 1536];
                    outB[(size_t)row * N + col] = f2bf(v + bias);
                } else {
                    v += b0[col] + resid[(size_t)row * N + col];
                    outF[(size_t)row * N + col] = v;
                }
            }
        }
    }
}

// ---------- kernel 4: banded attention, one wave per query ----------
__global__ __launch_bounds__(256)
void attn_kernel(const unsigned short* __restrict__ QKV,  // [M][2304] bf16: Q|K|V
                 unsigned short* __restrict__ ctx,        // [M][768] bf16
                 const int* __restrict__ level_p) {
    const int lane = threadIdx.x & 63;
    const int wv = threadIdx.x >> 6;
    int chunk = blockIdx.x;                 // B * NH * (S/4)
    int qi4 = chunk % 250;
    int h = (chunk / 250) % NH_;
    int b = chunk / (250 * NH_);
    int i = qi4 * 4 + wv;
    int lev = level_p[0];
    int w = (lev == 0) ? 2 : (lev == 1) ? 5 : S_;

    size_t mrow = (size_t)(b * S_ + i);
    float q = bf2f(QKV[mrow * HC_ + h * HD_ + lane]);
    int j0 = max(0, i - w), j1 = min(S_ - 1, i + w);

    float mx = -1e30f, l = 0.f, acc = 0.f;
    for (int j = j0; j <= j1; ++j) {
        size_t kr = (size_t)(b * S_ + j) * HC_ + 768 + h * HD_ + lane;
        float kv = bf2f(QKV[kr]);
        float p = q * kv;
#pragma unroll
        for (int o = 32; o; o >>= 1) p += __shfl_xor(p, o);
        p *= 0.125f;                         // 1/sqrt(64)
        float vv = bf2f(QKV[kr + 768]);
        float mn = fmaxf(mx, p);
        float corr = __expf(mx - mn);
        float e = __expf(p - mn);
        l = l * corr + e;
        acc = acc * corr + e * vv;
        mx = mn;
    }
    ctx[mrow * (size_t)H_ + h * HD_ + lane] = f2bf(acc / l);
}

// ---------- kernel 6: in-place LayerNorm over rows of d_out ----------
__global__ __launch_bounds__(256)
void ln_kernel(float* __restrict__ y, const float* __restrict__ g, const float* __restrict__ bta) {
    int row = blockIdx.x;
    int tid = threadIdx.x;
    float* p = y + (size_t)row * H_;
    float v[3];
    float s = 0.f, s2 = 0.f;
#pragma unroll
    for (int t = 0; t < 3; ++t) {
        v[t] = p[tid + t * 256];
        s += v[t];
        s2 += v[t] * v[t];
    }
#pragma unroll
    for (int o = 32; o; o >>= 1) {
        s  += __shfl_xor(s, o);
        s2 += __shfl_xor(s2, o);
    }
    __shared__ float ss[4], ss2[4];
    if ((tid & 63) == 0) { ss[tid >> 6] = s; ss2[tid >> 6] = s2; }
    __syncthreads();
    s  = ss[0] + ss[1] + ss[2] + ss[3];
    s2 = ss2[0] + ss2[1] + ss2[2] + ss2[3];
    float mu = s * (1.f / H_);
    float var = s2 * (1.f / H_) - mu * mu;
    float rs = rsqrtf(var + 1e-5f);
#pragma unroll
    for (int t = 0; t < 3; ++t) {
        int c = tid + t * 256;
        p[c] = (v[t] - mu) * rs * g[c] + bta[c];
    }
}

// ---------- launch ----------
extern "C" void kernel_launch(void* const* d_in, const int* in_sizes, int n_in,
                              void* d_out, int out_size, void* d_ws, size_t ws_size,
                              hipStream_t stream) {
    const float* feat  = (const float*)d_in[0];
    const float* pos   = (const float*)d_in[1];
    const float* Wq    = (const float*)d_in[2];
    const float* bq    = (const float*)d_in[3];
    const float* Wk    = (const float*)d_in[4];
    const float* bk    = (const float*)d_in[5];
    const float* Wv    = (const float*)d_in[6];
    const float* bv    = (const float*)d_in[7];
    const float* Wo    = (const float*)d_in[8];
    const float* bo    = (const float*)d_in[9];
    const float* ln_g  = (const float*)d_in[10];
    const float* ln_b  = (const float*)d_in[11];
    const int*   level = (const int*)d_in[12];
    float* out = (float*)d_out;

    // workspace layout (bf16 buffers as ushort)
    char* ws = (char*)d_ws;
    unsigned short* xb   = (unsigned short*)ws;                      // [8000][768]
    unsigned short* Wcat = xb + (size_t)M_ * H_;                     // [3072][768] = Wq|Wk|Wv|Wo
    unsigned short* QKVb = Wcat + (size_t)4 * H_ * H_;               // [8000][2304]
    unsigned short* ctxb = QKVb + (size_t)M_ * HC_;                  // [8000][768]

    // 1) x = features + pos_emb * scale  (bf16)
    prep_x_kernel<<<(M_ * H_ / 4 + 255) / 256, 256, 0, stream>>>(feat, pos, level, xb);
    // 2) weights -> bf16
    wconv_kernel<<<(4 * H_ * H_ / 4 + 255) / 256, 256, 0, stream>>>(Wq, Wk, Wv, Wo, Wcat);
    // 3) QKV = x @ [Wq|Wk|Wv]^T + bias   (bf16 out)
    gemm_bt_kernel<0><<<dim3(HC_ / BN, (M_ + BM - 1) / BM), 256, 0, stream>>>(
        xb, Wcat, M_, HC_, H_, bq, bk, bv, nullptr, QKVb, nullptr);
    // 4) banded attention -> ctx (bf16)
    attn_kernel<<<B_ * NH_ * (S_ / 4), 256, 0, stream>>>(QKVb, ctxb, level);
    // 5) y = ctx @ Wo^T + bo + features  (fp32 into d_out)
    gemm_bt_kernel<1><<<dim3(H_ / BN, (M_ + BM - 1) / BM), 256, 0, stream>>>(
        ctxb, Wcat + (size_t)3 * H_ * H_, M_, H_, H_, bo, nullptr, nullptr, feat, nullptr, out);
    // 6) LayerNorm in place on d_out
    ln_kernel<<<M_, 256, 0, stream>>>(out, ln_g, ln_b);
}

// Round 3
// 135.359 us; speedup vs baseline: 1.4934x; 1.2988x over previous
//
#include <hip/hip_runtime.h>
#include <hip/hip_bf16.h>
#include <cstddef>

// ---------- types / helpers ----------
typedef __attribute__((ext_vector_type(8))) short bf16x8;
typedef __attribute__((ext_vector_type(4))) float f32x4;

static __device__ __forceinline__ unsigned short f2bf(float f) {
    unsigned int u = __float_as_uint(f);
    u += 0x7fffu + ((u >> 16) & 1u);
    return (unsigned short)(u >> 16);
}
static __device__ __forceinline__ float bf2f(unsigned short h) {
    return __uint_as_float(((unsigned int)h) << 16);
}

#define B_ 8
#define S_ 1000
#define H_ 768
#define NH_ 12
#define HD_ 64
#define M_ 8000
#define HC_ 2304   // 3*768

// ---------- kernel 1: x = features + pos_emb * scale, cast to bf16 ----------
__global__ __launch_bounds__(256)
void prep_x_kernel(const float* __restrict__ feat, const float* __restrict__ pos,
                   const int* __restrict__ level, unsigned short* __restrict__ xb) {
    size_t e = ((size_t)blockIdx.x * blockDim.x + threadIdx.x) * 4;
    if (e >= (size_t)M_ * H_) return;
    float sc = 1.0f + 0.1f * (float)level[0];
    const float4 f = *reinterpret_cast<const float4*>(&feat[e]);
    size_t pe = e % ((size_t)S_ * H_);
    const float4 p = *reinterpret_cast<const float4*>(&pos[pe]);
    ushort4 o;
    o.x = f2bf(f.x + sc * p.x);
    o.y = f2bf(f.y + sc * p.y);
    o.z = f2bf(f.z + sc * p.z);
    o.w = f2bf(f.w + sc * p.w);
    *reinterpret_cast<ushort4*>(&xb[e]) = o;
}

// ---------- kernel 2: cast Wq|Wk|Wv|Wo (each [768][768] row-major) to bf16, concat ----------
__global__ __launch_bounds__(256)
void wconv_kernel(const float* __restrict__ wq, const float* __restrict__ wk,
                  const float* __restrict__ wv, const float* __restrict__ wo,
                  unsigned short* __restrict__ dst) {
    size_t e = ((size_t)blockIdx.x * blockDim.x + threadIdx.x) * 4;
    const size_t WSZ = (size_t)H_ * H_;
    if (e >= 4 * WSZ) return;
    const float* src; size_t off;
    if (e < WSZ)          { src = wq; off = e; }
    else if (e < 2 * WSZ) { src = wk; off = e - WSZ; }
    else if (e < 3 * WSZ) { src = wv; off = e - 2 * WSZ; }
    else                  { src = wo; off = e - 3 * WSZ; }
    const float4 f = *reinterpret_cast<const float4*>(&src[off]);
    ushort4 o;
    o.x = f2bf(f.x); o.y = f2bf(f.y); o.z = f2bf(f.z); o.w = f2bf(f.w);
    *reinterpret_cast<ushort4*>(&dst[e]) = o;
}

// ---------- kernel 3/5: bf16 MFMA GEMM, BK=64, XOR-swizzled LDS ----------
// C = A[M,K]*B[N,K]^T + epilogue
// EPI 0: bias select over {b0,b1,b2} per 768-col group, write bf16 to outB
// EPI 1: bias b0 + residual, write fp32 to outF
#define BM 128
#define BN 128
#define BK 64

template<int EPI>
__global__ __launch_bounds__(256)
void gemm_bt_kernel(const unsigned short* __restrict__ A,  // [M][K] bf16
                    const unsigned short* __restrict__ B,  // [N][K] bf16
                    int M, int N, int K,
                    const float* __restrict__ b0, const float* __restrict__ b1,
                    const float* __restrict__ b2,
                    const float* __restrict__ resid,
                    unsigned short* __restrict__ outB, float* __restrict__ outF) {
    // Flat LDS: A tile = bytes [0,16384), B tile = [16384,32768).
    // Logical layout [128 rows][64 k], 128B rows, with 16B-slot XOR swizzle:
    //   phys_slot = log_slot ^ (row&7)  (applied on the global SOURCE address,
    //   LDS written linearly by global_load_lds; same XOR applied on reads)
    __shared__ bf16x8 lds8[2048];   // 32 KB
    char* ldsb = (char*)lds8;
    const int tid  = threadIdx.x;
    const int lane = tid & 63;
    const int wid  = tid >> 6;
    const int wm = wid >> 1, wn = wid & 1;          // 2x2 wave grid, 64x64 per wave
    const int bm = blockIdx.y * BM;
    const int bn = blockIdx.x * BN;
    const int fr = lane & 15, fq = lane >> 4;

    // staging: each 1KB gload chunk covers 8 rows; lane -> row=chunk*8+(lane>>3),
    // phys slot = lane&7; source logical slot = (lane&7) ^ ((lane>>3)&7)
    const int srow = lane >> 3;
    const int scol = ((lane & 7) ^ (srow & 7)) * 8;     // logical k-elem offset

    f32x4 acc[4][4] = {};

    for (int k0 = 0; k0 < K; k0 += BK) {
#pragma unroll
        for (int t = 0; t < 4; ++t) {
            const int c = wid * 4 + t;                   // chunk 0..15
            const int r = c * 8 + srow;
            int ar = bm + r;
            ar = ar < M ? ar : M - 1;                    // clamp: junk rows -> out-rows >= M (skipped)
            const unsigned short* ga = A + (size_t)ar * K + k0 + scol;
            __builtin_amdgcn_global_load_lds(
                (const __attribute__((address_space(1))) unsigned int*)ga,
                (__attribute__((address_space(3))) unsigned int*)(ldsb + c * 1024), 16, 0, 0);
            const int br = bn + r;                       // N multiple of 128
            const unsigned short* gb = B + (size_t)br * K + k0 + scol;
            __builtin_amdgcn_global_load_lds(
                (const __attribute__((address_space(1))) unsigned int*)gb,
                (__attribute__((address_space(3))) unsigned int*)(ldsb + 16384 + c * 1024), 16, 0, 0);
        }
        __syncthreads();

        bf16x8 af[4][2], bf[4][2];
#pragma unroll
        for (int m = 0; m < 4; ++m) {
            const int row = wm * 64 + m * 16 + fr;
#pragma unroll
            for (int x = 0; x < 2; ++x) {
                const int slot = (fq + x * 4) ^ (row & 7);
                af[m][x] = *reinterpret_cast<const bf16x8*>(ldsb + row * 128 + slot * 16);
            }
        }
#pragma unroll
        for (int n = 0; n < 4; ++n) {
            const int row = wn * 64 + n * 16 + fr;
#pragma unroll
            for (int x = 0; x < 2; ++x) {
                const int slot = (fq + x * 4) ^ (row & 7);
                bf[n][x] = *reinterpret_cast<const bf16x8*>(ldsb + 16384 + row * 128 + slot * 16);
            }
        }
#pragma unroll
        for (int m = 0; m < 4; ++m)
#pragma unroll
            for (int n = 0; n < 4; ++n)
#pragma unroll
                for (int x = 0; x < 2; ++x)
                    acc[m][n] = __builtin_amdgcn_mfma_f32_16x16x32_bf16(af[m][x], bf[n][x], acc[m][n], 0, 0, 0);
        __syncthreads();
    }

    // epilogue + store: C[row][col], row = bm+wm*64+m*16+fq*4+j, col = bn+wn*64+n*16+fr
#pragma unroll
    for (int m = 0; m < 4; ++m) {
#pragma unroll
        for (int n = 0; n < 4; ++n) {
            int col = bn + wn * 64 + n * 16 + fr;
#pragma unroll
            for (int j = 0; j < 4; ++j) {
                int row = bm + wm * 64 + m * 16 + fq * 4 + j;
                if (row >= M) continue;
                float v = acc[m][n][j];
                if (EPI == 0) {
                    float bias = (col < 768) ? b0[col] : (col < 1536) ? b1[col - 768] : b2[col - 1536];
                    outB[(size_t)row * N + col] = f2bf(v + bias);
                } else {
                    v += b0[col] + resid[(size_t)row * N + col];
                    outF[(size_t)row * N + col] = v;
                }
            }
        }
    }
}

// ---------- kernel 4: banded attention, 16 queries/wave, 4 lanes x 16 dims ----------
__global__ __launch_bounds__(256)
void attn_kernel(const unsigned short* __restrict__ QKV,  // [M][2304] bf16: Q|K|V
                 unsigned short* __restrict__ ctx,        // [M][768] bf16
                 const int* __restrict__ level_p) {
    const int lane = threadIdx.x & 63;
    const int wv = threadIdx.x >> 6;
    const int qiw = lane >> 2;              // query within wave, 0..15
    const int d0 = (lane & 3) * 16;         // this lane's 16 dims

    const int qt = blockIdx.x & 15;                 // 16 query tiles of 64
    const int h  = (blockIdx.x >> 4) % NH_;
    const int b  = blockIdx.x / (16 * NH_);
    const int i  = qt * 64 + wv * 16 + qiw;
    const bool valid = i < S_;
    const int iq = valid ? i : S_ - 1;

    const int lev = level_p[0];
    const int w = (lev == 0) ? 2 : (lev == 1) ? 5 : S_;

    // load 16 dims of q
    const size_t qoff = (size_t)(b * S_ + iq) * HC_ + h * HD_ + d0;
    bf16x8 qa = *reinterpret_cast<const bf16x8*>(&QKV[qoff]);
    bf16x8 qb = *reinterpret_cast<const bf16x8*>(&QKV[qoff + 8]);
    float qf[16];
#pragma unroll
    for (int t = 0; t < 8; ++t) {
        qf[t]     = bf2f((unsigned short)qa[t]);
        qf[t + 8] = bf2f((unsigned short)qb[t]);
    }

    const int j0 = max(0, i - w), j1 = min(S_ - 1, i + w);
    float mx = -1e30f, l = 0.f;
    float acc[16];
#pragma unroll
    for (int t = 0; t < 16; ++t) acc[t] = 0.f;

    for (int jc = j0; jc <= j1; jc += 5) {
        float s[5];
        int jj[5];
#pragma unroll
        for (int t = 0; t < 5; ++t) {
            const int j = jc + t;
            jj[t] = j <= j1 ? j : j1;
            const size_t koff = (size_t)(b * S_ + jj[t]) * HC_ + 768 + h * HD_ + d0;
            bf16x8 ka = *reinterpret_cast<const bf16x8*>(&QKV[koff]);
            bf16x8 kb = *reinterpret_cast<const bf16x8*>(&QKV[koff + 8]);
            float p = 0.f;
#pragma unroll
            for (int d = 0; d < 8; ++d) {
                p = fmaf(qf[d], bf2f((unsigned short)ka[d]), p);
                p = fmaf(qf[d + 8], bf2f((unsigned short)kb[d]), p);
            }
            s[t] = p;
        }
        // batched quad reduce: 2 shuffle rounds serve all queries and all 5 keys
#pragma unroll
        for (int t = 0; t < 5; ++t) s[t] += __shfl_xor(s[t], 1);
#pragma unroll
        for (int t = 0; t < 5; ++t) s[t] += __shfl_xor(s[t], 2);
#pragma unroll
        for (int t = 0; t < 5; ++t)
            s[t] = (jc + t <= j1) ? s[t] * 0.125f : -1e30f;   // 1/sqrt(64), mask tail

        float cm = fmaxf(fmaxf(fmaxf(s[0], s[1]), fmaxf(s[2], s[3])), s[4]);
        float nm = fmaxf(mx, cm);
        float corr = __expf(mx - nm);
        l *= corr;
#pragma unroll
        for (int t = 0; t < 16; ++t) acc[t] *= corr;
#pragma unroll
        for (int t = 0; t < 5; ++t) {
            const float e = __expf(s[t] - nm);                // masked -> 0
            l += e;
            const size_t voff = (size_t)(b * S_ + jj[t]) * HC_ + 1536 + h * HD_ + d0;
            bf16x8 va = *reinterpret_cast<const bf16x8*>(&QKV[voff]);
            bf16x8 vb = *reinterpret_cast<const bf16x8*>(&QKV[voff + 8]);
#pragma unroll
            for (int d = 0; d < 8; ++d) {
                acc[d]     = fmaf(e, bf2f((unsigned short)va[d]), acc[d]);
                acc[d + 8] = fmaf(e, bf2f((unsigned short)vb[d]), acc[d + 8]);
            }
        }
        mx = nm;
    }

    if (valid) {
        const float inv = 1.f / l;
        bf16x8 o0, o1;
#pragma unroll
        for (int t = 0; t < 8; ++t) {
            o0[t] = (short)f2bf(acc[t] * inv);
            o1[t] = (short)f2bf(acc[t + 8] * inv);
        }
        unsigned short* dst = &ctx[(size_t)(b * S_ + i) * H_ + h * HD_ + d0];
        *reinterpret_cast<bf16x8*>(dst) = o0;
        *reinterpret_cast<bf16x8*>(dst + 8) = o1;
    }
}

// ---------- kernel 6: in-place LayerNorm over rows of d_out ----------
__global__ __launch_bounds__(256)
void ln_kernel(float* __restrict__ y, const float* __restrict__ g, const float* __restrict__ bta) {
    int row = blockIdx.x;
    int tid = threadIdx.x;
    float* p = y + (size_t)row * H_;
    float v[3];
    float s = 0.f, s2 = 0.f;
#pragma unroll
    for (int t = 0; t < 3; ++t) {
        v[t] = p[tid + t * 256];
        s += v[t];
        s2 += v[t] * v[t];
    }
#pragma unroll
    for (int o = 32; o; o >>= 1) {
        s  += __shfl_xor(s, o);
        s2 += __shfl_xor(s2, o);
    }
    __shared__ float ss[4], ss2[4];
    if ((tid & 63) == 0) { ss[tid >> 6] = s; ss2[tid >> 6] = s2; }
    __syncthreads();
    s  = ss[0] + ss[1] + ss[2] + ss[3];
    s2 = ss2[0] + ss2[1] + ss2[2] + ss2[3];
    float mu = s * (1.f / H_);
    float var = s2 * (1.f / H_) - mu * mu;
    float rs = rsqrtf(var + 1e-5f);
#pragma unroll
    for (int t = 0; t < 3; ++t) {
        int c = tid + t * 256;
        p[c] = (v[t] - mu) * rs * g[c] + bta[c];
    }
}

// ---------- launch ----------
extern "C" void kernel_launch(void* const* d_in, const int* in_sizes, int n_in,
                              void* d_out, int out_size, void* d_ws, size_t ws_size,
                              hipStream_t stream) {
    const float* feat  = (const float*)d_in[0];
    const float* pos   = (const float*)d_in[1];
    const float* Wq    = (const float*)d_in[2];
    const float* bq    = (const float*)d_in[3];
    const float* Wk    = (const float*)d_in[4];
    const float* bk    = (const float*)d_in[5];
    const float* Wv    = (const float*)d_in[6];
    const float* bv    = (const float*)d_in[7];
    const float* Wo    = (const float*)d_in[8];
    const float* bo    = (const float*)d_in[9];
    const float* ln_g  = (const float*)d_in[10];
    const float* ln_b  = (const float*)d_in[11];
    const int*   level = (const int*)d_in[12];
    float* out = (float*)d_out;

    // workspace layout (bf16 buffers as ushort)
    char* ws = (char*)d_ws;
    unsigned short* xb   = (unsigned short*)ws;                      // [8000][768]
    unsigned short* Wcat = xb + (size_t)M_ * H_;                     // [3072][768] = Wq|Wk|Wv|Wo
    unsigned short* QKVb = Wcat + (size_t)4 * H_ * H_;               // [8000][2304]
    unsigned short* ctxb = QKVb + (size_t)M_ * HC_;                  // [8000][768]

    // 1) x = features + pos_emb * scale  (bf16)
    prep_x_kernel<<<(M_ * H_ / 4 + 255) / 256, 256, 0, stream>>>(feat, pos, level, xb);
    // 2) weights -> bf16
    wconv_kernel<<<(4 * H_ * H_ / 4 + 255) / 256, 256, 0, stream>>>(Wq, Wk, Wv, Wo, Wcat);
    // 3) QKV = x @ [Wq|Wk|Wv]^T + bias   (bf16 out)
    gemm_bt_kernel<0><<<dim3(HC_ / BN, (M_ + BM - 1) / BM), 256, 0, stream>>>(
        xb, Wcat, M_, HC_, H_, bq, bk, bv, nullptr, QKVb, nullptr);
    // 4) banded attention -> ctx (bf16)
    attn_kernel<<<B_ * NH_ * 16, 256, 0, stream>>>(QKVb, ctxb, level);
    // 5) y = ctx @ Wo^T + bo + features  (fp32 into d_out)
    gemm_bt_kernel<1><<<dim3(H_ / BN, (M_ + BM - 1) / BM), 256, 0, stream>>>(
        ctxb, Wcat + (size_t)3 * H_ * H_, M_, H_, H_, bo, nullptr, nullptr, feat, nullptr, out);
    // 6) LayerNorm in place on d_out
    ln_kernel<<<M_, 256, 0, stream>>>(out, ln_g, ln_b);
}

// Round 4
// 128.246 us; speedup vs baseline: 1.5762x; 1.0555x over previous
//
#include <hip/hip_runtime.h>
#include <hip/hip_bf16.h>
#include <cstddef>

// ---------- types / helpers ----------
typedef __attribute__((ext_vector_type(8))) short bf16x8;
typedef __attribute__((ext_vector_type(4))) float f32x4;

static __device__ __forceinline__ unsigned short f2bf(float f) {
    unsigned int u = __float_as_uint(f);
    u += 0x7fffu + ((u >> 16) & 1u);
    return (unsigned short)(u >> 16);
}
static __device__ __forceinline__ float bf2f(unsigned short h) {
    return __uint_as_float(((unsigned int)h) << 16);
}

#define B_ 8
#define S_ 1000
#define H_ 768
#define NH_ 12
#define HD_ 64
#define M_ 8000
#define HC_ 2304   // 3*768

// ---------- kernel 1: fused (x = features + pos*scale -> bf16) + (weights -> bf16) ----------
__global__ __launch_bounds__(256)
void prep_all_kernel(const float* __restrict__ feat, const float* __restrict__ pos,
                     const int* __restrict__ level, unsigned short* __restrict__ xb,
                     const float* __restrict__ wq, const float* __restrict__ wk,
                     const float* __restrict__ wv, const float* __restrict__ wo,
                     unsigned short* __restrict__ wdst) {
    const size_t NX = (size_t)M_ * H_ / 4;       // 1,536,000 float4 chunks
    const size_t WSZ = (size_t)H_ * H_;
    size_t gid = (size_t)blockIdx.x * blockDim.x + threadIdx.x;
    if (gid < NX) {
        size_t e = gid * 4;
        float sc = 1.0f + 0.1f * (float)level[0];
        const float4 f = *reinterpret_cast<const float4*>(&feat[e]);
        size_t pe = e % ((size_t)S_ * H_);
        const float4 p = *reinterpret_cast<const float4*>(&pos[pe]);
        ushort4 o;
        o.x = f2bf(f.x + sc * p.x);
        o.y = f2bf(f.y + sc * p.y);
        o.z = f2bf(f.z + sc * p.z);
        o.w = f2bf(f.w + sc * p.w);
        *reinterpret_cast<ushort4*>(&xb[e]) = o;
    } else {
        size_t e = (gid - NX) * 4;
        if (e >= 4 * WSZ) return;
        const float* src; size_t off;
        if (e < WSZ)          { src = wq; off = e; }
        else if (e < 2 * WSZ) { src = wk; off = e - WSZ; }
        else if (e < 3 * WSZ) { src = wv; off = e - 2 * WSZ; }
        else                  { src = wo; off = e - 3 * WSZ; }
        const float4 f = *reinterpret_cast<const float4*>(&src[off]);
        ushort4 o;
        o.x = f2bf(f.x); o.y = f2bf(f.y); o.z = f2bf(f.z); o.w = f2bf(f.w);
        *reinterpret_cast<ushort4*>(&wdst[e]) = o;
    }
}

// ---------- kernel 2/4: bf16 MFMA GEMM, BK=64, double-buffered counted-vmcnt pipeline ----------
// C = A[M,K]*B[N,K]^T + epilogue
// EPI 0: bias select over {b0,b1,b2} per 768-col group, write bf16 to outB
// EPI 1: bias b0 + residual, write fp32 to outF
#define BM 128
#define BN 128
#define BK 64

template<int EPI>
__global__ __launch_bounds__(256)
void gemm_bt_kernel(const unsigned short* __restrict__ A,  // [M][K] bf16
                    const unsigned short* __restrict__ B,  // [N][K] bf16
                    int M, int N, int K,
                    const float* __restrict__ b0, const float* __restrict__ b1,
                    const float* __restrict__ b2,
                    const float* __restrict__ resid,
                    unsigned short* __restrict__ outB, float* __restrict__ outF) {
    // Double-buffered flat LDS: buf b at [b*32768, b*32768+32768):
    //   A tile bytes [0,16384), B tile [16384,32768) within a buffer.
    // Logical [128 rows][64 k] (128B rows) with 16B-slot XOR swizzle
    // (swizzle applied on the global SOURCE address; LDS written linearly by
    //  global_load_lds; same XOR applied on ds_read side). Conflict-free.
    __shared__ bf16x8 lds8[4096];   // 64 KB
    char* ldsb = (char*)lds8;
    const int tid  = threadIdx.x;
    const int lane = tid & 63;
    const int wid  = tid >> 6;
    const int wm = wid >> 1, wn = wid & 1;          // 2x2 wave grid, 64x64 per wave
    const int fr = lane & 15, fq = lane >> 4;

    // bijective XCD swizzle (m204): contiguous grid chunk per XCD
    const int nwg = gridDim.x;
    const int q = nwg >> 3, r = nwg & 7;
    const int xcd = blockIdx.x & 7, idx = blockIdx.x >> 3;
    const int swz = (xcd < r) ? (xcd * (q + 1) + idx) : (r * (q + 1) + (xcd - r) * q + idx);
    const int ntn = N / BN;
    const int bm = (swz / ntn) * BM;
    const int bn = (swz % ntn) * BN;

    // staging: 1KB chunk = 8 rows; lane -> row = chunk*8 + (lane>>3), phys slot = lane&7,
    // source logical slot = (lane&7) ^ (row&7)
    const int srow = lane >> 3;
    const int scol = ((lane & 7) ^ (srow & 7)) * 8;     // logical k-elem offset

    auto stage = [&](int buf, int k0) {
        char* base = ldsb + buf * 32768;
#pragma unroll
        for (int t = 0; t < 4; ++t) {
            const int c = wid * 4 + t;                   // chunk 0..15
            const int rr = c * 8 + srow;
            int ar = bm + rr;
            ar = ar < M ? ar : M - 1;                    // clamp: junk rows -> out-rows >= M (skipped)
            const unsigned short* ga = A + (size_t)ar * K + k0 + scol;
            __builtin_amdgcn_global_load_lds(
                (const __attribute__((address_space(1))) unsigned int*)ga,
                (__attribute__((address_space(3))) unsigned int*)(base + c * 1024), 16, 0, 0);
            const int br = bn + rr;                      // N multiple of 128
            const unsigned short* gb = B + (size_t)br * K + k0 + scol;
            __builtin_amdgcn_global_load_lds(
                (const __attribute__((address_space(1))) unsigned int*)gb,
                (__attribute__((address_space(3))) unsigned int*)(base + 16384 + c * 1024), 16, 0, 0);
        }
    };

    f32x4 acc[4][4] = {};
    const int NT = K / BK;

    stage(0, 0);                                         // prologue: 8 loads in flight
    for (int t = 0; t < NT; ++t) {
        const int cur = t & 1;
        if (t + 1 < NT) {
            stage(cur ^ 1, (t + 1) * BK);                // 8 more in flight (16 total)
            asm volatile("s_waitcnt vmcnt(8)" ::: "memory");   // oldest 8 (cur) done
        } else {
            asm volatile("s_waitcnt vmcnt(0)" ::: "memory");
        }
        __builtin_amdgcn_s_barrier();                    // all waves' cur loads landed

        char* base = ldsb + cur * 32768;
        bf16x8 af[4][2], bfv[4][2];
#pragma unroll
        for (int m = 0; m < 4; ++m) {
            const int row = wm * 64 + m * 16 + fr;
#pragma unroll
            for (int x = 0; x < 2; ++x) {
                const int slot = (fq + x * 4) ^ (row & 7);
                af[m][x] = *reinterpret_cast<const bf16x8*>(base + row * 128 + slot * 16);
            }
        }
#pragma unroll
        for (int n = 0; n < 4; ++n) {
            const int row = wn * 64 + n * 16 + fr;
#pragma unroll
            for (int x = 0; x < 2; ++x) {
                const int slot = (fq + x * 4) ^ (row & 7);
                bfv[n][x] = *reinterpret_cast<const bf16x8*>(base + 16384 + row * 128 + slot * 16);
            }
        }
#pragma unroll
        for (int m = 0; m < 4; ++m)
#pragma unroll
            for (int n = 0; n < 4; ++n)
#pragma unroll
                for (int x = 0; x < 2; ++x)
                    acc[m][n] = __builtin_amdgcn_mfma_f32_16x16x32_bf16(af[m][x], bfv[n][x], acc[m][n], 0, 0, 0);
        __builtin_amdgcn_s_barrier();                    // reads done before buffer reuse
    }

    // epilogue + store: C[row][col], row = bm+wm*64+m*16+fq*4+j, col = bn+wn*64+n*16+fr
#pragma unroll
    for (int m = 0; m < 4; ++m) {
#pragma unroll
        for (int n = 0; n < 4; ++n) {
            int col = bn + wn * 64 + n * 16 + fr;
#pragma unroll
            for (int j = 0; j < 4; ++j) {
                int row = bm + wm * 64 + m * 16 + fq * 4 + j;
                if (row >= M) continue;
                float v = acc[m][n][j];
                if (EPI == 0) {
                    float bias = (col < 768) ? b0[col] : (col < 1536) ? b1[col - 768] : b2[col - 1536];
                    outB[(size_t)row * N + col] = f2bf(v + bias);
                } else {
                    v += b0[col] + resid[(size_t)row * N + col];
                    outF[(size_t)row * N + col] = v;
                }
            }
        }
    }
}

// ---------- kernel 3: banded attention, 16 queries/wave, 4 lanes x 16 dims ----------
__global__ __launch_bounds__(256)
void attn_kernel(const unsigned short* __restrict__ QKV,  // [M][2304] bf16: Q|K|V
                 unsigned short* __restrict__ ctx,        // [M][768] bf16
                 const int* __restrict__ level_p) {
    const int lane = threadIdx.x & 63;
    const int wv = threadIdx.x >> 6;
    const int qiw = lane >> 2;              // query within wave, 0..15
    const int d0 = (lane & 3) * 16;         // this lane's 16 dims

    const int qt = blockIdx.x & 15;                 // 16 query tiles of 64
    const int h  = (blockIdx.x >> 4) % NH_;
    const int b  = blockIdx.x / (16 * NH_);
    const int i  = qt * 64 + wv * 16 + qiw;
    const bool valid = i < S_;
    const int iq = valid ? i : S_ - 1;

    const int lev = level_p[0];
    const int w = (lev == 0) ? 2 : (lev == 1) ? 5 : S_;

    // load 16 dims of q
    const size_t qoff = (size_t)(b * S_ + iq) * HC_ + h * HD_ + d0;
    bf16x8 qa = *reinterpret_cast<const bf16x8*>(&QKV[qoff]);
    bf16x8 qb = *reinterpret_cast<const bf16x8*>(&QKV[qoff + 8]);
    float qf[16];
#pragma unroll
    for (int t = 0; t < 8; ++t) {
        qf[t]     = bf2f((unsigned short)qa[t]);
        qf[t + 8] = bf2f((unsigned short)qb[t]);
    }

    const int j0 = max(0, i - w), j1 = min(S_ - 1, i + w);
    float mx = -1e30f, l = 0.f;
    float acc[16];
#pragma unroll
    for (int t = 0; t < 16; ++t) acc[t] = 0.f;

    for (int jc = j0; jc <= j1; jc += 5) {
        float s[5];
        int jj[5];
#pragma unroll
        for (int t = 0; t < 5; ++t) {
            const int j = jc + t;
            jj[t] = j <= j1 ? j : j1;
            const size_t koff = (size_t)(b * S_ + jj[t]) * HC_ + 768 + h * HD_ + d0;
            bf16x8 ka = *reinterpret_cast<const bf16x8*>(&QKV[koff]);
            bf16x8 kb = *reinterpret_cast<const bf16x8*>(&QKV[koff + 8]);
            float p = 0.f;
#pragma unroll
            for (int d = 0; d < 8; ++d) {
                p = fmaf(qf[d], bf2f((unsigned short)ka[d]), p);
                p = fmaf(qf[d + 8], bf2f((unsigned short)kb[d]), p);
            }
            s[t] = p;
        }
        // batched quad reduce: 2 shuffle rounds serve all queries and all 5 keys
#pragma unroll
        for (int t = 0; t < 5; ++t) s[t] += __shfl_xor(s[t], 1);
#pragma unroll
        for (int t = 0; t < 5; ++t) s[t] += __shfl_xor(s[t], 2);
#pragma unroll
        for (int t = 0; t < 5; ++t)
            s[t] = (jc + t <= j1) ? s[t] * 0.125f : -1e30f;   // 1/sqrt(64), mask tail

        float cm = fmaxf(fmaxf(fmaxf(s[0], s[1]), fmaxf(s[2], s[3])), s[4]);
        float nm = fmaxf(mx, cm);
        float corr = __expf(mx - nm);
        l *= corr;
#pragma unroll
        for (int t = 0; t < 16; ++t) acc[t] *= corr;
#pragma unroll
        for (int t = 0; t < 5; ++t) {
            const float e = __expf(s[t] - nm);                // masked -> 0
            l += e;
            const size_t voff = (size_t)(b * S_ + jj[t]) * HC_ + 1536 + h * HD_ + d0;
            bf16x8 va = *reinterpret_cast<const bf16x8*>(&QKV[voff]);
            bf16x8 vb = *reinterpret_cast<const bf16x8*>(&QKV[voff + 8]);
#pragma unroll
            for (int d = 0; d < 8; ++d) {
                acc[d]     = fmaf(e, bf2f((unsigned short)va[d]), acc[d]);
                acc[d + 8] = fmaf(e, bf2f((unsigned short)vb[d]), acc[d + 8]);
            }
        }
        mx = nm;
    }

    if (valid) {
        const float inv = 1.f / l;
        bf16x8 o0, o1;
#pragma unroll
        for (int t = 0; t < 8; ++t) {
            o0[t] = (short)f2bf(acc[t] * inv);
            o1[t] = (short)f2bf(acc[t + 8] * inv);
        }
        unsigned short* dst = &ctx[(size_t)(b * S_ + i) * H_ + h * HD_ + d0];
        *reinterpret_cast<bf16x8*>(dst) = o0;
        *reinterpret_cast<bf16x8*>(dst + 8) = o1;
    }
}

// ---------- kernel 5: in-place LayerNorm over rows of d_out ----------
__global__ __launch_bounds__(256)
void ln_kernel(float* __restrict__ y, const float* __restrict__ g, const float* __restrict__ bta) {
    int row = blockIdx.x;
    int tid = threadIdx.x;
    float* p = y + (size_t)row * H_;
    float v[3];
    float s = 0.f, s2 = 0.f;
#pragma unroll
    for (int t = 0; t < 3; ++t) {
        v[t] = p[tid + t * 256];
        s += v[t];
        s2 += v[t] * v[t];
    }
#pragma unroll
    for (int o = 32; o; o >>= 1) {
        s  += __shfl_xor(s, o);
        s2 += __shfl_xor(s2, o);
    }
    __shared__ float ss[4], ss2[4];
    if ((tid & 63) == 0) { ss[tid >> 6] = s; ss2[tid >> 6] = s2; }
    __syncthreads();
    s  = ss[0] + ss[1] + ss[2] + ss[3];
    s2 = ss2[0] + ss2[1] + ss2[2] + ss2[3];
    float mu = s * (1.f / H_);
    float var = s2 * (1.f / H_) - mu * mu;
    float rs = rsqrtf(var + 1e-5f);
#pragma unroll
    for (int t = 0; t < 3; ++t) {
        int c = tid + t * 256;
        p[c] = (v[t] - mu) * rs * g[c] + bta[c];
    }
}

// ---------- launch ----------
extern "C" void kernel_launch(void* const* d_in, const int* in_sizes, int n_in,
                              void* d_out, int out_size, void* d_ws, size_t ws_size,
                              hipStream_t stream) {
    const float* feat  = (const float*)d_in[0];
    const float* pos   = (const float*)d_in[1];
    const float* Wq    = (const float*)d_in[2];
    const float* bq    = (const float*)d_in[3];
    const float* Wk    = (const float*)d_in[4];
    const float* bk    = (const float*)d_in[5];
    const float* Wv    = (const float*)d_in[6];
    const float* bv    = (const float*)d_in[7];
    const float* Wo    = (const float*)d_in[8];
    const float* bo    = (const float*)d_in[9];
    const float* ln_g  = (const float*)d_in[10];
    const float* ln_b  = (const float*)d_in[11];
    const int*   level = (const int*)d_in[12];
    float* out = (float*)d_out;

    // workspace layout (bf16 buffers as ushort)
    char* ws = (char*)d_ws;
    unsigned short* xb   = (unsigned short*)ws;                      // [8000][768]
    unsigned short* Wcat = xb + (size_t)M_ * H_;                     // [3072][768] = Wq|Wk|Wv|Wo
    unsigned short* QKVb = Wcat + (size_t)4 * H_ * H_;               // [8000][2304]
    unsigned short* ctxb = QKVb + (size_t)M_ * HC_;                  // [8000][768]

    // 1) fused x-prep + weight cast
    const int nprep = (int)(((size_t)M_ * H_ / 4 + (size_t)4 * H_ * H_ / 4 + 255) / 256);
    prep_all_kernel<<<nprep, 256, 0, stream>>>(feat, pos, level, xb, Wq, Wk, Wv, Wo, Wcat);
    // 2) QKV = x @ [Wq|Wk|Wv]^T + bias   (bf16 out)
    gemm_bt_kernel<0><<<(HC_ / BN) * ((M_ + BM - 1) / BM), 256, 0, stream>>>(
        xb, Wcat, M_, HC_, H_, bq, bk, bv, nullptr, QKVb, nullptr);
    // 3) banded attention -> ctx (bf16)
    attn_kernel<<<B_ * NH_ * 16, 256, 0, stream>>>(QKVb, ctxb, level);
    // 4) y = ctx @ Wo^T + bo + features  (fp32 into d_out)
    gemm_bt_kernel<1><<<(H_ / BN) * ((M_ + BM - 1) / BM), 256, 0, stream>>>(
        ctxb, Wcat + (size_t)3 * H_ * H_, M_, H_, H_, bo, nullptr, nullptr, feat, nullptr, out);
    // 5) LayerNorm in place on d_out
    ln_kernel<<<M_, 256, 0, stream>>>(out, ln_g, ln_b);
}

// Round 5
// 127.140 us; speedup vs baseline: 1.5899x; 1.0087x over previous
//
#include <hip/hip_runtime.h>
#include <hip/hip_bf16.h>
#include <cstddef>

// ---------- types / helpers ----------
typedef __attribute__((ext_vector_type(8))) short bf16x8;
typedef __attribute__((ext_vector_type(4))) float f32x4;

static __device__ __forceinline__ unsigned short f2bf(float f) {
    unsigned int u = __float_as_uint(f);
    u += 0x7fffu + ((u >> 16) & 1u);
    return (unsigned short)(u >> 16);
}
static __device__ __forceinline__ float bf2f(unsigned short h) {
    return __uint_as_float(((unsigned int)h) << 16);
}

#define B_ 8
#define S_ 1000
#define H_ 768
#define NH_ 12
#define HD_ 64
#define M_ 8000
#define HC_ 2304   // 3*768

// ---------- kernel 1: fused (x = features + pos*scale -> bf16) + (weights -> bf16) ----------
__global__ __launch_bounds__(256)
void prep_all_kernel(const float* __restrict__ feat, const float* __restrict__ pos,
                     const int* __restrict__ level, unsigned short* __restrict__ xb,
                     const float* __restrict__ wq, const float* __restrict__ wk,
                     const float* __restrict__ wv, const float* __restrict__ wo,
                     unsigned short* __restrict__ wdst) {
    const size_t NX = (size_t)M_ * H_ / 4;       // 1,536,000 float4 chunks
    const size_t WSZ = (size_t)H_ * H_;
    size_t gid = (size_t)blockIdx.x * blockDim.x + threadIdx.x;
    if (gid < NX) {
        size_t e = gid * 4;
        float sc = 1.0f + 0.1f * (float)level[0];
        const float4 f = *reinterpret_cast<const float4*>(&feat[e]);
        size_t pe = e % ((size_t)S_ * H_);
        const float4 p = *reinterpret_cast<const float4*>(&pos[pe]);
        ushort4 o;
        o.x = f2bf(f.x + sc * p.x);
        o.y = f2bf(f.y + sc * p.y);
        o.z = f2bf(f.z + sc * p.z);
        o.w = f2bf(f.w + sc * p.w);
        *reinterpret_cast<ushort4*>(&xb[e]) = o;
    } else {
        size_t e = (gid - NX) * 4;
        if (e >= 4 * WSZ) return;
        const float* src; size_t off;
        if (e < WSZ)          { src = wq; off = e; }
        else if (e < 2 * WSZ) { src = wk; off = e - WSZ; }
        else if (e < 3 * WSZ) { src = wv; off = e - 2 * WSZ; }
        else                  { src = wo; off = e - 3 * WSZ; }
        const float4 f = *reinterpret_cast<const float4*>(&src[off]);
        ushort4 o;
        o.x = f2bf(f.x); o.y = f2bf(f.y); o.z = f2bf(f.z); o.w = f2bf(f.w);
        *reinterpret_cast<ushort4*>(&wdst[e]) = o;
    }
}

// ---------- kernel 2/4: bf16 MFMA GEMM, BK=32, dbuf + counted vmcnt, 32KB LDS ----------
// C = A[M,K]*B[N,K]^T + epilogue
// EPI 0: bias select over {b0,b1,b2} per 768-col group, write bf16 to outB
// EPI 1: bias b0 + residual, write fp32 to outF
#define BM 128
#define BN 128
#define BK 32

template<int EPI>
__global__ __launch_bounds__(256)
void gemm_bt_kernel(const unsigned short* __restrict__ A,  // [M][K] bf16
                    const unsigned short* __restrict__ B,  // [N][K] bf16
                    int M, int N, int K,
                    const float* __restrict__ b0, const float* __restrict__ b1,
                    const float* __restrict__ b2,
                    const float* __restrict__ resid,
                    unsigned short* __restrict__ outB, float* __restrict__ outF) {
    // Double-buffered flat LDS, 16 KB per buffer:
    //   A tile bytes [0,8192), B tile [8192,16384) within a buffer.
    // Logical [128 rows][32 k] (64B rows = 4x16B slots) with 2-bit XOR swizzle:
    //   phys_slot = log_slot ^ ((row>>1)&3)
    // Applied on the global SOURCE address (LDS written linearly by
    // global_load_lds) and on the ds_read side. Per-quarter-wave reads land
    // 2 lanes/bank = conflict-free.
    __shared__ bf16x8 lds8[2048];   // 32 KB
    char* ldsb = (char*)lds8;
    const int tid  = threadIdx.x;
    const int lane = tid & 63;
    const int wid  = tid >> 6;
    const int wm = wid >> 1, wn = wid & 1;          // 2x2 wave grid, 64x64 per wave
    const int fr = lane & 15, fq = lane >> 4;

    // bijective XCD swizzle (m204): contiguous grid chunk per XCD
    const int nwg = gridDim.x;
    const int q = nwg >> 3, r = nwg & 7;
    const int xcd = blockIdx.x & 7, idx = blockIdx.x >> 3;
    const int swz = (xcd < r) ? (xcd * (q + 1) + idx) : (r * (q + 1) + (xcd - r) * q + idx);
    const int ntn = N / BN;
    const int bm = (swz / ntn) * BM;
    const int bn = (swz % ntn) * BN;

    // staging: 1KB chunk = 16 rows; lane -> row = chunk*16 + (lane>>2),
    // phys slot = lane&3, source logical slot = (lane&3) ^ ((lane>>3)&3)
    const int srow = lane >> 2;
    const int scol = ((lane & 3) ^ ((lane >> 3) & 3)) * 8;   // logical k-elem offset

    auto stage = [&](int buf, int k0) {
        char* base = ldsb + buf * 16384;
#pragma unroll
        for (int t = 0; t < 2; ++t) {
            const int c = wid * 2 + t;                   // chunk 0..7
            const int rr = c * 16 + srow;
            int ar = bm + rr;
            ar = ar < M ? ar : M - 1;                    // clamp: junk rows -> out-rows >= M (skipped)
            const unsigned short* ga = A + (size_t)ar * K + k0 + scol;
            __builtin_amdgcn_global_load_lds(
                (const __attribute__((address_space(1))) unsigned int*)ga,
                (__attribute__((address_space(3))) unsigned int*)(base + c * 1024), 16, 0, 0);
            const int br = bn + rr;                      // N multiple of 128
            const unsigned short* gb = B + (size_t)br * K + k0 + scol;
            __builtin_amdgcn_global_load_lds(
                (const __attribute__((address_space(1))) unsigned int*)gb,
                (__attribute__((address_space(3))) unsigned int*)(base + 8192 + c * 1024), 16, 0, 0);
        }
    };

    f32x4 acc[4][4] = {};
    const int NT = K / BK;

    stage(0, 0);                                         // prologue: 4 loads in flight
    for (int t = 0; t < NT; ++t) {
        const int cur = t & 1;
        if (t + 1 < NT) {
            stage(cur ^ 1, (t + 1) * BK);                // 4 more in flight (8 total)
            asm volatile("s_waitcnt vmcnt(4)" ::: "memory");   // oldest 4 (cur) done
        } else {
            asm volatile("s_waitcnt vmcnt(0)" ::: "memory");
        }
        __builtin_amdgcn_s_barrier();                    // all waves' cur loads landed

        char* base = ldsb + cur * 16384;
        bf16x8 af[4], bfv[4];
#pragma unroll
        for (int m = 0; m < 4; ++m) {
            const int row = wm * 64 + m * 16 + fr;
            const int slot = fq ^ ((fr >> 1) & 3);
            af[m] = *reinterpret_cast<const bf16x8*>(base + row * 64 + slot * 16);
        }
#pragma unroll
        for (int n = 0; n < 4; ++n) {
            const int row = wn * 64 + n * 16 + fr;
            const int slot = fq ^ ((fr >> 1) & 3);
            bfv[n] = *reinterpret_cast<const bf16x8*>(base + 8192 + row * 64 + slot * 16);
        }
#pragma unroll
        for (int m = 0; m < 4; ++m)
#pragma unroll
            for (int n = 0; n < 4; ++n)
                acc[m][n] = __builtin_amdgcn_mfma_f32_16x16x32_bf16(af[m], bfv[n], acc[m][n], 0, 0, 0);
        __builtin_amdgcn_s_barrier();                    // reads done before buffer reuse
    }

    // epilogue + store: C[row][col], row = bm+wm*64+m*16+fq*4+j, col = bn+wn*64+n*16+fr
#pragma unroll
    for (int m = 0; m < 4; ++m) {
#pragma unroll
        for (int n = 0; n < 4; ++n) {
            int col = bn + wn * 64 + n * 16 + fr;
#pragma unroll
            for (int j = 0; j < 4; ++j) {
                int row = bm + wm * 64 + m * 16 + fq * 4 + j;
                if (row >= M) continue;
                float v = acc[m][n][j];
                if (EPI == 0) {
                    float bias = (col < 768) ? b0[col] : (col < 1536) ? b1[col - 768] : b2[col - 1536];
                    outB[(size_t)row * N + col] = f2bf(v + bias);
                } else {
                    v += b0[col] + resid[(size_t)row * N + col];
                    outF[(size_t)row * N + col] = v;
                }
            }
        }
    }
}

// ---------- kernel 3: banded attention, 16 queries/wave, 4 lanes x 16 dims ----------
__global__ __launch_bounds__(256)
void attn_kernel(const unsigned short* __restrict__ QKV,  // [M][2304] bf16: Q|K|V
                 unsigned short* __restrict__ ctx,        // [M][768] bf16
                 const int* __restrict__ level_p) {
    const int lane = threadIdx.x & 63;
    const int wv = threadIdx.x >> 6;
    const int qiw = lane >> 2;              // query within wave, 0..15
    const int d0 = (lane & 3) * 16;         // this lane's 16 dims

    const int qt = blockIdx.x & 15;                 // 16 query tiles of 64
    const int h  = (blockIdx.x >> 4) % NH_;
    const int b  = blockIdx.x / (16 * NH_);
    const int i  = qt * 64 + wv * 16 + qiw;
    const bool valid = i < S_;
    const int iq = valid ? i : S_ - 1;

    const int lev = level_p[0];
    const int w = (lev == 0) ? 2 : (lev == 1) ? 5 : S_;

    // load 16 dims of q
    const size_t qoff = (size_t)(b * S_ + iq) * HC_ + h * HD_ + d0;
    bf16x8 qa = *reinterpret_cast<const bf16x8*>(&QKV[qoff]);
    bf16x8 qb = *reinterpret_cast<const bf16x8*>(&QKV[qoff + 8]);
    float qf[16];
#pragma unroll
    for (int t = 0; t < 8; ++t) {
        qf[t]     = bf2f((unsigned short)qa[t]);
        qf[t + 8] = bf2f((unsigned short)qb[t]);
    }

    const int j0 = max(0, i - w), j1 = min(S_ - 1, i + w);
    float mx = -1e30f, l = 0.f;
    float acc[16];
#pragma unroll
    for (int t = 0; t < 16; ++t) acc[t] = 0.f;

    for (int jc = j0; jc <= j1; jc += 5) {
        float s[5];
        int jj[5];
#pragma unroll
        for (int t = 0; t < 5; ++t) {
            const int j = jc + t;
            jj[t] = j <= j1 ? j : j1;
            const size_t koff = (size_t)(b * S_ + jj[t]) * HC_ + 768 + h * HD_ + d0;
            bf16x8 ka = *reinterpret_cast<const bf16x8*>(&QKV[koff]);
            bf16x8 kb = *reinterpret_cast<const bf16x8*>(&QKV[koff + 8]);
            float p = 0.f;
#pragma unroll
            for (int d = 0; d < 8; ++d) {
                p = fmaf(qf[d], bf2f((unsigned short)ka[d]), p);
                p = fmaf(qf[d + 8], bf2f((unsigned short)kb[d]), p);
            }
            s[t] = p;
        }
        // batched quad reduce: 2 shuffle rounds serve all queries and all 5 keys
#pragma unroll
        for (int t = 0; t < 5; ++t) s[t] += __shfl_xor(s[t], 1);
#pragma unroll
        for (int t = 0; t < 5; ++t) s[t] += __shfl_xor(s[t], 2);
#pragma unroll
        for (int t = 0; t < 5; ++t)
            s[t] = (jc + t <= j1) ? s[t] * 0.125f : -1e30f;   // 1/sqrt(64), mask tail

        float cm = fmaxf(fmaxf(fmaxf(s[0], s[1]), fmaxf(s[2], s[3])), s[4]);
        float nm = fmaxf(mx, cm);
        float corr = __expf(mx - nm);
        l *= corr;
#pragma unroll
        for (int t = 0; t < 16; ++t) acc[t] *= corr;
#pragma unroll
        for (int t = 0; t < 5; ++t) {
            const float e = __expf(s[t] - nm);                // masked -> 0
            l += e;
            const size_t voff = (size_t)(b * S_ + jj[t]) * HC_ + 1536 + h * HD_ + d0;
            bf16x8 va = *reinterpret_cast<const bf16x8*>(&QKV[voff]);
            bf16x8 vb = *reinterpret_cast<const bf16x8*>(&QKV[voff + 8]);
#pragma unroll
            for (int d = 0; d < 8; ++d) {
                acc[d]     = fmaf(e, bf2f((unsigned short)va[d]), acc[d]);
                acc[d + 8] = fmaf(e, bf2f((unsigned short)vb[d]), acc[d + 8]);
            }
        }
        mx = nm;
    }

    if (valid) {
        const float inv = 1.f / l;
        bf16x8 o0, o1;
#pragma unroll
        for (int t = 0; t < 8; ++t) {
            o0[t] = (short)f2bf(acc[t] * inv);
            o1[t] = (short)f2bf(acc[t + 8] * inv);
        }
        unsigned short* dst = &ctx[(size_t)(b * S_ + i) * H_ + h * HD_ + d0];
        *reinterpret_cast<bf16x8*>(dst) = o0;
        *reinterpret_cast<bf16x8*>(dst + 8) = o1;
    }
}

// ---------- kernel 5: in-place LayerNorm over rows of d_out ----------
__global__ __launch_bounds__(256)
void ln_kernel(float* __restrict__ y, const float* __restrict__ g, const float* __restrict__ bta) {
    int row = blockIdx.x;
    int tid = threadIdx.x;
    float* p = y + (size_t)row * H_;
    float v[3];
    float s = 0.f, s2 = 0.f;
#pragma unroll
    for (int t = 0; t < 3; ++t) {
        v[t] = p[tid + t * 256];
        s += v[t];
        s2 += v[t] * v[t];
    }
#pragma unroll
    for (int o = 32; o; o >>= 1) {
        s  += __shfl_xor(s, o);
        s2 += __shfl_xor(s2, o);
    }
    __shared__ float ss[4], ss2[4];
    if ((tid & 63) == 0) { ss[tid >> 6] = s; ss2[tid >> 6] = s2; }
    __syncthreads();
    s  = ss[0] + ss[1] + ss[2] + ss[3];
    s2 = ss2[0] + ss2[1] + ss2[2] + ss2[3];
    float mu = s * (1.f / H_);
    float var = s2 * (1.f / H_) - mu * mu;
    float rs = rsqrtf(var + 1e-5f);
#pragma unroll
    for (int t = 0; t < 3; ++t) {
        int c = tid + t * 256;
        p[c] = (v[t] - mu) * rs * g[c] + bta[c];
    }
}

// ---------- launch ----------
extern "C" void kernel_launch(void* const* d_in, const int* in_sizes, int n_in,
                              void* d_out, int out_size, void* d_ws, size_t ws_size,
                              hipStream_t stream) {
    const float* feat  = (const float*)d_in[0];
    const float* pos   = (const float*)d_in[1];
    const float* Wq    = (const float*)d_in[2];
    const float* bq    = (const float*)d_in[3];
    const float* Wk    = (const float*)d_in[4];
    const float* bk    = (const float*)d_in[5];
    const float* Wv    = (const float*)d_in[6];
    const float* bv    = (const float*)d_in[7];
    const float* Wo    = (const float*)d_in[8];
    const float* bo    = (const float*)d_in[9];
    const float* ln_g  = (const float*)d_in[10];
    const float* ln_b  = (const float*)d_in[11];
    const int*   level = (const int*)d_in[12];
    float* out = (float*)d_out;

    // workspace layout (bf16 buffers as ushort)
    char* ws = (char*)d_ws;
    unsigned short* xb   = (unsigned short*)ws;                      // [8000][768]
    unsigned short* Wcat = xb + (size_t)M_ * H_;                     // [3072][768] = Wq|Wk|Wv|Wo
    unsigned short* QKVb = Wcat + (size_t)4 * H_ * H_;               // [8000][2304]
    unsigned short* ctxb = QKVb + (size_t)M_ * HC_;                  // [8000][768]

    // 1) fused x-prep + weight cast
    const int nprep = (int)(((size_t)M_ * H_ / 4 + (size_t)4 * H_ * H_ / 4 + 255) / 256);
    prep_all_kernel<<<nprep, 256, 0, stream>>>(feat, pos, level, xb, Wq, Wk, Wv, Wo, Wcat);
    // 2) QKV = x @ [Wq|Wk|Wv]^T + bias   (bf16 out)
    gemm_bt_kernel<0><<<(HC_ / BN) * ((M_ + BM - 1) / BM), 256, 0, stream>>>(
        xb, Wcat, M_, HC_, H_, bq, bk, bv, nullptr, QKVb, nullptr);
    // 3) banded attention -> ctx (bf16)
    attn_kernel<<<B_ * NH_ * 16, 256, 0, stream>>>(QKVb, ctxb, level);
    // 4) y = ctx @ Wo^T + bo + features  (fp32 into d_out)
    gemm_bt_kernel<1><<<(H_ / BN) * ((M_ + BM - 1) / BM), 256, 0, stream>>>(
        ctxb, Wcat + (size_t)3 * H_ * H_, M_, H_, H_, bo, nullptr, nullptr, feat, nullptr, out);
    // 5) LayerNorm in place on d_out
    ln_kernel<<<M_, 256, 0, stream>>>(out, ln_g, ln_b);
}